// Round 15
// baseline (154.315 us; speedup 1.0000x reference)
//
#include <hip/hip_runtime.h>
#include <hip/hip_bf16.h>

// B=32, S=2048, D=1024, C=256
//   top[b,s] = max_c sum_d (latent[c,d]*att_diag[d]) * (tm*embeds[b,s,d] + pos_table[rel+64,d])
//   p = softmax_s(top*m + (m-1)*NEG);  ctx[b,d] = tok_diag[d] * sum_s embeds*p
//
// R15 = R11 skeleton + exact WP-fold:
//   logit = (tm*W)*e + WP[c,pid],  WP = W*pos_table^T (f32, exact).
// Main loop per wave per kc: 4 stage gload_lds + 4 e-loads only (pos gone),
// build = cvt/sub split of raw e (no fmaf), 32 MFMA (2-term fp16 split),
// counted-vmcnt barrier (wait 4 stage; 4 e stay in flight).
// Flash epilogue adds WP before the c-max; k_finish combines partials.
//
// ws: whi 512K | wpt 256K | partial 2M | mblk 2K | zblk 2K

#define HC 64
#define NEGV 1000000000000.0f

constexpr int Bb = 32, Ss = 2048, Dd = 1024, Cc = 256;
constexpr int NKC = 32;                 // k-chunks of 32
constexpr int CT = Cc / 16;             // 16 c-tiles
constexpr int NBLK = 16;                // 128-token blocks per batch

typedef _Float16 f16x8 __attribute__((ext_vector_type(8)));
typedef float    f32x4 __attribute__((ext_vector_type(4)));

// ---------------- Pass 0a: W' = tm*latent*att_diag -> fp16 frag chunks ----
// layout: whi[kc][ct][lane][8] (16KB/kc)
// A-frag map: lane = (c%16) + 16*g holds A[c][k = kc*32 + 8g + i]
__global__ __launch_bounds__(256) void k_prep_w(
    const float* __restrict__ latent, const float* __restrict__ att_diag,
    const float* __restrict__ tok_mult, _Float16* __restrict__ whi)
{
    const int idx = blockIdx.x * 256 + threadIdx.x;   // c*Dd + k
    const int c = idx >> 10, k = idx & 1023;
    const float wv = tok_mult[0] * latent[idx] * att_diag[k];
    const int kc = k >> 5, g = (k >> 3) & 3, i = k & 7;
    const int lane = (c & 15) + 16 * g, ct = c >> 4;
    whi[(size_t)kc * 8192 + (size_t)ct * 512 + lane * 8 + i] = (_Float16)wv;
}

// ---------------- Pass 0b: WP[pid][c] = sum_d latent[c,d]*att[d]*pos[pid,d]
// (exact f32; 132 blocks, ~5us; proven in R5/R6 runs)
__global__ __launch_bounds__(256) void k_wp(
    const float* __restrict__ latent, const float* __restrict__ att_diag,
    const float* __restrict__ pos_table, float* __restrict__ wpt)
{
    __shared__ float pa[1024];
    const int pid = blockIdx.x;        // 0..131
    const int t = threadIdx.x;
    {
        f32x4 p4 = *(const f32x4*)(pos_table + (size_t)pid * Dd + t * 4);
        f32x4 a4 = *(const f32x4*)(att_diag + t * 4);
        *(f32x4*)&pa[t * 4] = p4 * a4;
    }
    __syncthreads();
    const int wv = t >> 6, l = t & 63;
    float pav[16];
    #pragma unroll
    for (int q = 0; q < 4; q++) *(f32x4*)&pav[q * 4] = *(const f32x4*)&pa[l * 16 + q * 4];
    for (int c = wv; c < Cc; c += 4) {
        const float* lrow = latent + (size_t)c * Dd + l * 16;
        float s = 0.f;
        #pragma unroll
        for (int q = 0; q < 4; q++) {
            f32x4 lv = *(const f32x4*)(lrow + q * 4);
            s = fmaf(lv[0], pav[q * 4 + 0], s);
            s = fmaf(lv[1], pav[q * 4 + 1], s);
            s = fmaf(lv[2], pav[q * 4 + 2], s);
            s = fmaf(lv[3], pav[q * 4 + 3], s);
        }
        #pragma unroll
        for (int o = 32; o >= 1; o >>= 1) s += __shfl_xor(s, o);
        if (l == 0) wpt[pid * Cc + c] = s;
    }
}

// ------- Pass 1: scores via MFMA, block max/sumexp, flash ctx partial -----
__global__ __launch_bounds__(256, 2) void k_scores_mfma(
    const float* __restrict__ embeds,    // [B][S][D]
    const float* __restrict__ mask,      // [B][S]
    const int*   __restrict__ rel_ids,   // [B][S]
    const _Float16* __restrict__ whi,    // [NKC][CT][64][8]
    const float* __restrict__ wpt,       // [132][256]
    float* __restrict__ partial,         // [B][NBLK][D]
    float* __restrict__ mblk,            // [B][NBLK]
    float* __restrict__ zblk)            // [B][NBLK]
{
    __shared__ _Float16 sbuf[2][8192];   // 2 x 16KB (W chunks)
    __shared__ float l_sh[128];
    __shared__ float w_sh[128];
    __shared__ float red2[2], zred[2];

    const int t  = threadIdx.x;
    const int wv = t >> 6;      // wave 0..3
    const int l  = t & 63;
    const int lr = l & 15;      // token within set / output col
    const int lg = l >> 4;      // k-group

    const int b   = blockIdx.x >> 4;     // 16 blocks of 128 tokens per batch
    const int blk = blockIdx.x & 15;
    const int s0  = blk * 128;

    const float* erow[2];
    int pid[2];
    #pragma unroll
    for (int st = 0; st < 2; st++) {
        const int tok = s0 + wv * 32 + st * 16 + lr;
        erow[st] = embeds + ((size_t)b * Ss + tok) * Dd;
        pid[st]  = rel_ids[b * Ss + tok] + HC;
    }

    f32x4 acc[CT][2];
    #pragma unroll
    for (int ct = 0; ct < CT; ct++)
        #pragma unroll
        for (int st = 0; st < 2; st++) acc[ct][st] = (f32x4){0.f, 0.f, 0.f, 0.f};

    // e prefetch registers (one kc ahead): 4 global loads per call
    f32x4 e0[2], e1[2];
    auto loadE = [&](int kc) {
        const int k0 = kc * 32 + lg * 8;
        #pragma unroll
        for (int st = 0; st < 2; st++) {
            e0[st] = *(const f32x4*)(erow[st] + k0);
            e1[st] = *(const f32x4*)(erow[st] + k0 + 4);
        }
    };

    // stage one 16KB W chunk: 16 wave-chunks of 1KB (4 per wave)
    auto stage = [&](int kc, _Float16* dst) {
        const _Float16* src = whi + (size_t)kc * 8192;
        #pragma unroll
        for (int i = 0; i < 4; i++) {
            const int off = (i * 4 + wv) << 9;   // elems; 1KB chunks
            __builtin_amdgcn_global_load_lds(
                (const __attribute__((address_space(1))) void*)(src + off + l * 8),
                (__attribute__((address_space(3))) void*)(dst + off),
                16, 0, 0);
        }
    };

    // prologue: stage first (oldest), then e
    stage(0, sbuf[0]);
    loadE(0);
    asm volatile("s_waitcnt vmcnt(4)" ::: "memory");  // stage(0) landed
    __builtin_amdgcn_s_barrier();

    int cur = 0;
    for (int kc = 0; kc < NKC; kc++) {
        if (kc + 1 < NKC) stage(kc + 1, sbuf[cur ^ 1]);   // oldest VMEM this iter

        // split current e into fp16 hi/lo B-frags (no merge fmaf: tm in W)
        f16x8 bh[2], bl[2];
        #pragma unroll
        for (int st = 0; st < 2; st++) {
            float e[8];
            *(f32x4*)&e[0] = e0[st]; *(f32x4*)&e[4] = e1[st];
            #pragma unroll
            for (int i = 0; i < 8; i++) {
                const _Float16 h = (_Float16)e[i];
                bh[st][i] = h;
                bl[st][i] = (_Float16)(e[i] - (float)h);
            }
        }
        if (kc + 1 < NKC) loadE(kc + 1);   // 4 HBM loads; stay in flight past barrier

        const _Float16* base = sbuf[cur];
        #pragma unroll
        for (int ct = 0; ct < CT; ct++) {
            const f16x8 ah = *(const f16x8*)(base + ct * 512 + l * 8);
            #pragma unroll
            for (int st = 0; st < 2; st++) {
                acc[ct][st] = __builtin_amdgcn_mfma_f32_16x16x32_f16(ah, bh[st], acc[ct][st], 0, 0, 0);
                acc[ct][st] = __builtin_amdgcn_mfma_f32_16x16x32_f16(ah, bl[st], acc[ct][st], 0, 0, 0);
            }
        }
        // wait only for this iter's 4 stage loads; e(kc+1) stays in flight
        asm volatile("s_waitcnt vmcnt(4)" ::: "memory");
        __builtin_amdgcn_s_barrier();
        cur ^= 1;
    }

    // add WP (exact pos term) and max over c -> masked logit per token
    // C/D map: col = lane&15 (token), row = lg*4 + r  ->  c = ct*16 + lg*4 + r
    #pragma unroll
    for (int st = 0; st < 2; st++) {
        const float* wrow = wpt + pid[st] * Cc + lg * 4;
        float mx = -3.4e38f;
        #pragma unroll
        for (int ct = 0; ct < CT; ct++) {
            const f32x4 wp = *(const f32x4*)(wrow + ct * 16);
            #pragma unroll
            for (int r = 0; r < 4; r++) mx = fmaxf(mx, acc[ct][st][r] + wp[r]);
        }
        mx = fmaxf(mx, __shfl_xor(mx, 16));
        mx = fmaxf(mx, __shfl_xor(mx, 32));
        if (lg == 0) {
            const int si = wv * 32 + st * 16 + lr;   // token within block
            const int s  = s0 + si;
            const float mk = mask[b * Ss + s];
            l_sh[si] = mx * mk + (mk - 1.0f) * NEGV;
        }
    }
    __syncthreads();

    // block max M_b over the 128 logits
    if (t < 128) {
        float v = l_sh[t];
        #pragma unroll
        for (int o = 32; o >= 1; o >>= 1) v = fmaxf(v, __shfl_xor(v, o));
        if ((t & 63) == 0) red2[t >> 6] = v;
    }
    __syncthreads();
    const float Mb = fmaxf(red2[0], red2[1]);
    if (t < 128) w_sh[t] = expf(l_sh[t] - Mb);
    __syncthreads();
    if (t < 128) {
        float z = w_sh[t];
        #pragma unroll
        for (int o = 32; o >= 1; o >>= 1) z += __shfl_xor(z, o);
        if ((t & 63) == 0) zred[t >> 6] = z;
    }
    __syncthreads();

    // block-local ctx partial: P[d] = sum_s w_sh[s] * e[s0+s][d]  (L2-hot)
    {
        const float* eb = embeds + ((size_t)b * Ss + s0) * Dd + t * 4;
        f32x4 ca = (f32x4){0.f, 0.f, 0.f, 0.f};
        #pragma unroll 8
        for (int s = 0; s < 128; s++) {
            const float wgt = w_sh[s];
            const f32x4 ev = *(const f32x4*)(eb + (size_t)s * Dd);
            ca[0] = fmaf(wgt, ev[0], ca[0]);
            ca[1] = fmaf(wgt, ev[1], ca[1]);
            ca[2] = fmaf(wgt, ev[2], ca[2]);
            ca[3] = fmaf(wgt, ev[3], ca[3]);
        }
        *(f32x4*)(partial + ((size_t)(b * NBLK + blk)) * Dd + t * 4) = ca;
        if (t == 0) {
            mblk[b * NBLK + blk] = Mb;
            zblk[b * NBLK + blk] = zred[0] + zred[1];
        }
    }
}

// ------- Pass 2: global flash combine + tok_diag -------
__global__ __launch_bounds__(256) void k_finish(
    const float* __restrict__ mblk, const float* __restrict__ zblk,
    const float* __restrict__ partial, const float* __restrict__ tok_diag,
    float* __restrict__ out)
{
    __shared__ float cf[NBLK];
    const int b = blockIdx.x, t = threadIdx.x;

    if (t < 64) {
        const float mv = (t < NBLK) ? mblk[b * NBLK + t] : -3.4e38f;
        float M = mv;
        #pragma unroll
        for (int o = 32; o >= 1; o >>= 1) M = fmaxf(M, __shfl_xor(M, o));
        const float zv = (t < NBLK) ? zblk[b * NBLK + t] * expf(mv - M) : 0.f;
        float Z = zv;
        #pragma unroll
        for (int o = 32; o >= 1; o >>= 1) Z += __shfl_xor(Z, o);
        if (t < NBLK) cf[t] = expf(mv - M) / Z;
    }
    __syncthreads();

    const int d = t * 4;
    f32x4 a = (f32x4){0.f, 0.f, 0.f, 0.f};
    #pragma unroll
    for (int j = 0; j < NBLK; j++) {
        const float c = cf[j];
        const f32x4 p = *(const f32x4*)(partial + ((size_t)(b * NBLK + j)) * Dd + d);
        a[0] = fmaf(c, p[0], a[0]);
        a[1] = fmaf(c, p[1], a[1]);
        a[2] = fmaf(c, p[2], a[2]);
        a[3] = fmaf(c, p[3], a[3]);
    }
    const f32x4 td = *(const f32x4*)(tok_diag + d);
    f32x4 o = a * td;
    *(f32x4*)(out + (size_t)b * Dd + d) = o;
}

extern "C" void kernel_launch(void* const* d_in, const int* in_sizes, int n_in,
                              void* d_out, int out_size, void* d_ws, size_t ws_size,
                              hipStream_t stream) {
    const float* embeds    = (const float*)d_in[0];
    const float* mask      = (const float*)d_in[1];
    const float* latent    = (const float*)d_in[2];
    const float* att_diag  = (const float*)d_in[3];
    const float* tok_diag  = (const float*)d_in[4];
    const float* pos_table = (const float*)d_in[5];
    const float* tok_mult  = (const float*)d_in[6];
    const int*   rel_ids   = (const int*)d_in[7];
    float* out = (float*)d_out;

    char* ws = (char*)d_ws;
    _Float16* whi    = (_Float16*)(ws);              // 512 KB
    float*    wpt    = (float*)(ws + 524288);        // 256 KB (135K used)
    float*    partial= (float*)(ws + 786432);        // 2 MB
    float*    mblk   = (float*)(ws + 2883584);       // 2 KB
    float*    zblk   = (float*)(ws + 2885632);       // 2 KB

    k_prep_w<<<(Cc * Dd) / 256, 256, 0, stream>>>(latent, att_diag, tok_mult, whi);
    k_wp<<<132, 256, 0, stream>>>(latent, att_diag, pos_table, wpt);
    k_scores_mfma<<<Bb * NBLK, 256, 0, stream>>>(
        embeds, mask, rel_ids, whi, wpt, partial, mblk, zblk);
    k_finish<<<Bb, 256, 0, stream>>>(mblk, zblk, partial, tok_diag, out);
}

// Round 16
// 149.366 us; speedup vs baseline: 1.0331x; 1.0331x over previous
//
#include <hip/hip_runtime.h>
#include <hip/hip_bf16.h>

// B=32, S=2048, D=1024, C=256
//   top[b,s] = max_c sum_d (latent[c,d]*att_diag[d]) * (tm*embeds[b,s,d] + pos_table[rel+64,d])
//   p = softmax_s(top*m + (m-1)*NEG);  ctx[b,d] = tok_diag[d] * sum_s embeds*p
//
// R16: barrier-free main loop. No LDS staging: A-fragments (W_hi, 512KB,
// L2-resident, fragment-ordered) are read per-wave directly from L2 as
// coalesced 16B/lane loads; 4 MFMAs per fragment. e/p prefetched one kc
// ahead in A/B register sets (unroll x2). Zero s_barrier in the K-loop ->
// waves self-schedule, compiler pipelines freely.
// 2-term split-fp16 MFMA: W_hi*(x_hi+x_lo), x = tm*e + p (f32 merge).
// Flash epilogue per 128-token block (M_b, Z_b, P); k_finish combines.
//
// ws: whi 512K | partial 2M | mblk 2K | zblk 2K

#define HC 64
#define NEGV 1000000000000.0f

constexpr int Bb = 32, Ss = 2048, Dd = 1024, Cc = 256;
constexpr int NKC = 32;                 // k-chunks of 32
constexpr int CT = Cc / 16;             // 16 c-tiles
constexpr int NBLK = 16;                // 128-token blocks per batch

typedef _Float16 f16x8 __attribute__((ext_vector_type(8)));
typedef float    f32x4 __attribute__((ext_vector_type(4)));

// ---------------- Pass 0: W_hi -> fragment-ordered chunks ----------
// layout: whi[(kc*CT + ct)*512 + lane*8 + i]
// A-frag map: lane = (c%16) + 16*g holds A[c][k = kc*32 + 8g + i]
__global__ __launch_bounds__(256) void k_prep_w(
    const float* __restrict__ latent, const float* __restrict__ att_diag,
    _Float16* __restrict__ whi)
{
    const int idx = blockIdx.x * 256 + threadIdx.x;   // c*Dd + k
    const int c = idx >> 10, k = idx & 1023;
    const float wv = latent[idx] * att_diag[k];
    const int kc = k >> 5, g = (k >> 3) & 3, i = k & 7;
    const int lane = (c & 15) + 16 * g, ct = c >> 4;
    whi[(size_t)(kc * CT + ct) * 512 + lane * 8 + i] = (_Float16)wv;
}

// ------- Pass 1: scores via MFMA (L2-direct A), flash ctx partial -----
__global__ __launch_bounds__(256, 2) void k_scores_mfma(
    const float* __restrict__ embeds,    // [B][S][D]
    const float* __restrict__ mask,      // [B][S]
    const float* __restrict__ pos_table, // [132][D]
    const float* __restrict__ tok_mult,  // [1]
    const int*   __restrict__ rel_ids,   // [B][S]
    const _Float16* __restrict__ whi,    // [NKC*CT][64][8]
    float* __restrict__ partial,         // [B][NBLK][D]
    float* __restrict__ mblk,            // [B][NBLK]
    float* __restrict__ zblk)            // [B][NBLK]
{
    __shared__ float l_sh[128];
    __shared__ float w_sh[128];
    __shared__ float red2[2], zred[2];

    const int t  = threadIdx.x;
    const int wv = t >> 6;      // wave 0..3
    const int l  = t & 63;
    const int lr = l & 15;      // token within set / output col
    const int lg = l >> 4;      // k-group

    const int b   = blockIdx.x >> 4;     // 16 blocks of 128 tokens per batch
    const int blk = blockIdx.x & 15;
    const int s0  = blk * 128;

    const float tm = tok_mult[0];

    const float* erow[2];
    const float* prow[2];
    #pragma unroll
    for (int st = 0; st < 2; st++) {
        const int tok = s0 + wv * 32 + st * 16 + lr;
        erow[st] = embeds + ((size_t)b * Ss + tok) * Dd;
        prow[st] = pos_table + (size_t)(rel_ids[b * Ss + tok] + HC) * Dd;
    }

    f32x4 acc[CT][2];
    #pragma unroll
    for (int ct = 0; ct < CT; ct++)
        #pragma unroll
        for (int st = 0; st < 2; st++) acc[ct][st] = (f32x4){0.f, 0.f, 0.f, 0.f};

    // A/B e/p prefetch register sets (one kc ahead; 8 loads per set)
    f32x4 eA0[2], eA1[2], pA0[2], pA1[2];
    f32x4 eB0[2], eB1[2], pB0[2], pB1[2];
    auto loadA = [&](int kc) {
        const int k0 = kc * 32 + lg * 8;
        #pragma unroll
        for (int st = 0; st < 2; st++) {
            eA0[st] = *(const f32x4*)(erow[st] + k0);
            eA1[st] = *(const f32x4*)(erow[st] + k0 + 4);
            pA0[st] = *(const f32x4*)(prow[st] + k0);
            pA1[st] = *(const f32x4*)(prow[st] + k0 + 4);
        }
    };
    auto loadB = [&](int kc) {
        const int k0 = kc * 32 + lg * 8;
        #pragma unroll
        for (int st = 0; st < 2; st++) {
            eB0[st] = *(const f32x4*)(erow[st] + k0);
            eB1[st] = *(const f32x4*)(erow[st] + k0 + 4);
            pB0[st] = *(const f32x4*)(prow[st] + k0);
            pB1[st] = *(const f32x4*)(prow[st] + k0 + 4);
        }
    };

    const f16x8* whi8 = (const f16x8*)whi;   // [ (kc*CT+ct)*64 + l ]

    // one kc body: build frags from given e/p regs, 16 L2 ah loads, 64 MFMA
    auto body = [&](int kc, const f32x4* E0, const f32x4* E1,
                    const f32x4* P0, const f32x4* P1) {
        f16x8 bh[2], bl[2];
        #pragma unroll
        for (int st = 0; st < 2; st++) {
            float e[8], p[8];
            *(f32x4*)&e[0] = E0[st]; *(f32x4*)&e[4] = E1[st];
            *(f32x4*)&p[0] = P0[st]; *(f32x4*)&p[4] = P1[st];
            #pragma unroll
            for (int i = 0; i < 8; i++) {
                const float x = fmaf(tm, e[i], p[i]);
                const _Float16 h = (_Float16)x;
                bh[st][i] = h;
                bl[st][i] = (_Float16)(x - (float)h);
            }
        }
        const int fbase = kc * (CT * 64) + l;
        #pragma unroll
        for (int ct = 0; ct < CT; ct++) {
            const f16x8 ah = whi8[fbase + ct * 64];   // L2-direct, coalesced 1KB/wave
            #pragma unroll
            for (int st = 0; st < 2; st++) {
                acc[ct][st] = __builtin_amdgcn_mfma_f32_16x16x32_f16(ah, bh[st], acc[ct][st], 0, 0, 0);
                acc[ct][st] = __builtin_amdgcn_mfma_f32_16x16x32_f16(ah, bl[st], acc[ct][st], 0, 0, 0);
            }
        }
    };

    // barrier-free pipelined K-loop (unroll x2, A/B rotation)
    loadA(0);
    for (int kc = 0; kc < NKC; kc += 2) {
        if (kc + 1 < NKC) loadB(kc + 1);
        body(kc, eA0, eA1, pA0, pA1);
        if (kc + 2 < NKC) loadA(kc + 2);
        body(kc + 1, eB0, eB1, pB0, pB1);
    }

    // masked logit per token -> LDS
    #pragma unroll
    for (int st = 0; st < 2; st++) {
        float mx = acc[0][st][0];
        #pragma unroll
        for (int ct = 0; ct < CT; ct++)
            #pragma unroll
            for (int r = 0; r < 4; r++) mx = fmaxf(mx, acc[ct][st][r]);
        mx = fmaxf(mx, __shfl_xor(mx, 16));
        mx = fmaxf(mx, __shfl_xor(mx, 32));
        if (lg == 0) {
            const int si = wv * 32 + st * 16 + lr;   // token within block
            const int s  = s0 + si;
            const float mk = mask[b * Ss + s];
            l_sh[si] = mx * mk + (mk - 1.0f) * NEGV;
        }
    }
    __syncthreads();

    // block max M_b over the 128 logits
    if (t < 128) {
        float v = l_sh[t];
        #pragma unroll
        for (int o = 32; o >= 1; o >>= 1) v = fmaxf(v, __shfl_xor(v, o));
        if ((t & 63) == 0) red2[t >> 6] = v;
    }
    __syncthreads();
    const float Mb = fmaxf(red2[0], red2[1]);
    if (t < 128) w_sh[t] = expf(l_sh[t] - Mb);
    __syncthreads();
    if (t < 128) {
        float z = w_sh[t];
        #pragma unroll
        for (int o = 32; o >= 1; o >>= 1) z += __shfl_xor(z, o);
        if ((t & 63) == 0) zred[t >> 6] = z;
    }
    __syncthreads();

    // block-local ctx partial: P[d] = sum_s w_sh[s] * e[s0+s][d]  (L2-hot)
    {
        const float* eb = embeds + ((size_t)b * Ss + s0) * Dd + t * 4;
        f32x4 ca = (f32x4){0.f, 0.f, 0.f, 0.f};
        #pragma unroll 8
        for (int s = 0; s < 128; s++) {
            const float wgt = w_sh[s];
            const f32x4 ev = *(const f32x4*)(eb + (size_t)s * Dd);
            ca[0] = fmaf(wgt, ev[0], ca[0]);
            ca[1] = fmaf(wgt, ev[1], ca[1]);
            ca[2] = fmaf(wgt, ev[2], ca[2]);
            ca[3] = fmaf(wgt, ev[3], ca[3]);
        }
        *(f32x4*)(partial + ((size_t)(b * NBLK + blk)) * Dd + t * 4) = ca;
        if (t == 0) {
            mblk[b * NBLK + blk] = Mb;
            zblk[b * NBLK + blk] = zred[0] + zred[1];
        }
    }
}

// ------- Pass 2: global flash combine + tok_diag -------
__global__ __launch_bounds__(256) void k_finish(
    const float* __restrict__ mblk, const float* __restrict__ zblk,
    const float* __restrict__ partial, const float* __restrict__ tok_diag,
    float* __restrict__ out)
{
    __shared__ float cf[NBLK];
    const int b = blockIdx.x, t = threadIdx.x;

    if (t < 64) {
        const float mv = (t < NBLK) ? mblk[b * NBLK + t] : -3.4e38f;
        float M = mv;
        #pragma unroll
        for (int o = 32; o >= 1; o >>= 1) M = fmaxf(M, __shfl_xor(M, o));
        const float zv = (t < NBLK) ? zblk[b * NBLK + t] * expf(mv - M) : 0.f;
        float Z = zv;
        #pragma unroll
        for (int o = 32; o >= 1; o >>= 1) Z += __shfl_xor(Z, o);
        if (t < NBLK) cf[t] = expf(mv - M) / Z;
    }
    __syncthreads();

    const int d = t * 4;
    f32x4 a = (f32x4){0.f, 0.f, 0.f, 0.f};
    #pragma unroll
    for (int j = 0; j < NBLK; j++) {
        const float c = cf[j];
        const f32x4 p = *(const f32x4*)(partial + ((size_t)(b * NBLK + j)) * Dd + d);
        a[0] = fmaf(c, p[0], a[0]);
        a[1] = fmaf(c, p[1], a[1]);
        a[2] = fmaf(c, p[2], a[2]);
        a[3] = fmaf(c, p[3], a[3]);
    }
    const f32x4 td = *(const f32x4*)(tok_diag + d);
    f32x4 o = a * td;
    *(f32x4*)(out + (size_t)b * Dd + d) = o;
}

extern "C" void kernel_launch(void* const* d_in, const int* in_sizes, int n_in,
                              void* d_out, int out_size, void* d_ws, size_t ws_size,
                              hipStream_t stream) {
    const float* embeds    = (const float*)d_in[0];
    const float* mask      = (const float*)d_in[1];
    const float* latent    = (const float*)d_in[2];
    const float* att_diag  = (const float*)d_in[3];
    const float* tok_diag  = (const float*)d_in[4];
    const float* pos_table = (const float*)d_in[5];
    const float* tok_mult  = (const float*)d_in[6];
    const int*   rel_ids   = (const int*)d_in[7];
    float* out = (float*)d_out;

    char* ws = (char*)d_ws;
    _Float16* whi    = (_Float16*)(ws);              // 512 KB
    float*    partial= (float*)(ws + 524288);        // 2 MB
    float*    mblk   = (float*)(ws + 2621440);       // 2 KB
    float*    zblk   = (float*)(ws + 2623488);       // 2 KB

    k_prep_w<<<(Cc * Dd) / 256, 256, 0, stream>>>(latent, att_diag, whi);
    k_scores_mfma<<<Bb * NBLK, 256, 0, stream>>>(
        embeds, mask, pos_table, tok_mult, rel_ids, whi, partial, mblk, zblk);
    k_finish<<<Bb, 256, 0, stream>>>(mblk, zblk, partial, tok_diag, out);
}

// Round 17
// 129.732 us; speedup vs baseline: 1.1895x; 1.1513x over previous
//
#include <hip/hip_runtime.h>
#include <hip/hip_bf16.h>

// B=32, S=2048, D=1024, C=256
//   top[b,s] = max_c sum_d (latent[c,d]*att_diag[d]) * (tm*embeds[b,s,d] + pos_table[rel+64,d])
//   p = softmax_s(top*m + (m-1)*NEG);  ctx[b,d] = tok_diag[d] * sum_s embeds*p
//
// R17 = R11 + smoothed VMEM issue. The 8 e/p prefetch loads for kc+1 are
// spread one-per-even-ct through the 16-ct MFMA loop (HBM e first, L1-hot
// pos last), pinned via sched_group_barrier {DS_READ 1, VMEM 1, MFMA 4}
// per iteration -> no per-kc miss burst (MSHR saturation theory).
// vmcnt(8) at the barrier: stage drained, all 8 e/p stay in flight.
// 2-term split-fp16 MFMA: W_hi*(x_hi+x_lo), x = tm*e + p (f32 merge).
// Flash epilogue per 128-token block (M_b, Z_b, P); k_finish combines.
//
// ws: whi 512K | partial 2M | mblk 2K | zblk 2K

#define HC 64
#define NEGV 1000000000000.0f

constexpr int Bb = 32, Ss = 2048, Dd = 1024, Cc = 256;
constexpr int NKC = 32;                 // k-chunks of 32
constexpr int CT = Cc / 16;             // 16 c-tiles
constexpr int NBLK = 16;                // 128-token blocks per batch

typedef _Float16 f16x8 __attribute__((ext_vector_type(8)));
typedef float    f32x4 __attribute__((ext_vector_type(4)));

// ---------------- Pass 0: W_hi -> per-kc fragment chunks ----------
// layout: whi[kc][ct][lane][8] (16KB/kc)
// A-frag map: lane = (c%16) + 16*g holds A[c][k = kc*32 + 8g + i]
__global__ __launch_bounds__(256) void k_prep_w(
    const float* __restrict__ latent, const float* __restrict__ att_diag,
    _Float16* __restrict__ whi)
{
    const int idx = blockIdx.x * 256 + threadIdx.x;   // c*Dd + k
    const int c = idx >> 10, k = idx & 1023;
    const float wv = latent[idx] * att_diag[k];
    const int kc = k >> 5, g = (k >> 3) & 3, i = k & 7;
    const int lane = (c & 15) + 16 * g, ct = c >> 4;
    whi[(size_t)kc * 8192 + (size_t)ct * 512 + lane * 8 + i] = (_Float16)wv;
}

// ------- Pass 1: scores via MFMA, block max/sumexp, flash ctx partial -----
__global__ __launch_bounds__(256, 2) void k_scores_mfma(
    const float* __restrict__ embeds,    // [B][S][D]
    const float* __restrict__ mask,      // [B][S]
    const float* __restrict__ pos_table, // [132][D]
    const float* __restrict__ tok_mult,  // [1]
    const int*   __restrict__ rel_ids,   // [B][S]
    const _Float16* __restrict__ whi,    // [NKC][CT][64][8]
    float* __restrict__ partial,         // [B][NBLK][D]
    float* __restrict__ mblk,            // [B][NBLK]
    float* __restrict__ zblk)            // [B][NBLK]
{
    __shared__ _Float16 sbuf[2][8192];   // 2 x 16KB (W_hi chunks)
    __shared__ float l_sh[128];
    __shared__ float w_sh[128];
    __shared__ float red2[2], zred[2];

    const int t  = threadIdx.x;
    const int wv = t >> 6;      // wave 0..3
    const int l  = t & 63;
    const int lr = l & 15;      // token within set / output col
    const int lg = l >> 4;      // k-group

    const int b   = blockIdx.x >> 4;     // 16 blocks of 128 tokens per batch
    const int blk = blockIdx.x & 15;
    const int s0  = blk * 128;

    const float tm = tok_mult[0];

    const float* erow[2];
    const float* prow[2];
    #pragma unroll
    for (int st = 0; st < 2; st++) {
        const int tok = s0 + wv * 32 + st * 16 + lr;
        erow[st] = embeds + ((size_t)b * Ss + tok) * Dd;
        prow[st] = pos_table + (size_t)(rel_ids[b * Ss + tok] + HC) * Dd;
    }

    f32x4 acc[CT][2];
    #pragma unroll
    for (int ct = 0; ct < CT; ct++)
        #pragma unroll
        for (int st = 0; st < 2; st++) acc[ct][st] = (f32x4){0.f, 0.f, 0.f, 0.f};

    // e/p prefetch registers (one kc ahead); loads spread through MFMA loop
    f32x4 e0[2], e1[2], p0[2], p1[2];
    auto loadEP = [&](int kc) {   // prologue only
        const int k0 = kc * 32 + lg * 8;
        #pragma unroll
        for (int st = 0; st < 2; st++) {
            e0[st] = *(const f32x4*)(erow[st] + k0);
            e1[st] = *(const f32x4*)(erow[st] + k0 + 4);
            p0[st] = *(const f32x4*)(prow[st] + k0);
            p1[st] = *(const f32x4*)(prow[st] + k0 + 4);
        }
    };

    // stage one 16KB W_hi chunk: 16 wave-chunks of 1KB (4 per wave)
    auto stage = [&](int kc, _Float16* dst) {
        const _Float16* src = whi + (size_t)kc * 8192;
        #pragma unroll
        for (int i = 0; i < 4; i++) {
            const int off = (i * 4 + wv) << 9;   // elems; 1KB chunks
            __builtin_amdgcn_global_load_lds(
                (const __attribute__((address_space(1))) void*)(src + off + l * 8),
                (__attribute__((address_space(3))) void*)(dst + off),
                16, 0, 0);
        }
    };

    // prologue: stage first (oldest), then e/p
    stage(0, sbuf[0]);
    loadEP(0);
    asm volatile("s_waitcnt vmcnt(8)" ::: "memory");  // stage(0) landed
    __builtin_amdgcn_s_barrier();

    int cur = 0;
    for (int kc = 0; kc < NKC; kc++) {
        stage((kc + 1 < NKC) ? kc + 1 : kc, sbuf[cur ^ 1]);   // 4 loads, oldest this iter

        // build current B frags (e split hi/lo fp16); consumes e/p(kc) regs
        f16x8 bh[2], bl[2];
        #pragma unroll
        for (int st = 0; st < 2; st++) {
            float e[8], p[8];
            *(f32x4*)&e[0] = e0[st]; *(f32x4*)&e[4] = e1[st];
            *(f32x4*)&p[0] = p0[st]; *(f32x4*)&p[4] = p1[st];
            #pragma unroll
            for (int i = 0; i < 8; i++) {
                const float x = fmaf(tm, e[i], p[i]);
                const _Float16 h = (_Float16)x;
                bh[st][i] = h;
                bl[st][i] = (_Float16)(x - (float)h);
            }
        }

        // next-kc load addresses (clamped in-bounds on last iter; redundant then)
        const int kcn = (kc + 1 < NKC) ? kc + 1 : NKC - 1;
        const int k0n = kcn * 32 + lg * 8;

        const _Float16* base = sbuf[cur];
        #pragma unroll
        for (int ct = 0; ct < CT; ct++) {
            const f16x8 ah = *(const f16x8*)(base + ct * 512 + l * 8);
            // smoothed VMEM: one prefetch load per even ct (HBM e first, L1-hot p last)
            switch (ct) {
                case 0:  e0[0] = *(const f32x4*)(erow[0] + k0n);     break;
                case 2:  e1[0] = *(const f32x4*)(erow[0] + k0n + 4); break;
                case 4:  e0[1] = *(const f32x4*)(erow[1] + k0n);     break;
                case 6:  e1[1] = *(const f32x4*)(erow[1] + k0n + 4); break;
                case 8:  p0[0] = *(const f32x4*)(prow[0] + k0n);     break;
                case 10: p1[0] = *(const f32x4*)(prow[0] + k0n + 4); break;
                case 12: p0[1] = *(const f32x4*)(prow[1] + k0n);     break;
                case 14: p1[1] = *(const f32x4*)(prow[1] + k0n + 4); break;
                default: break;
            }
            acc[ct][0] = __builtin_amdgcn_mfma_f32_16x16x32_f16(ah, bh[0], acc[ct][0], 0, 0, 0);
            acc[ct][0] = __builtin_amdgcn_mfma_f32_16x16x32_f16(ah, bl[0], acc[ct][0], 0, 0, 0);
            acc[ct][1] = __builtin_amdgcn_mfma_f32_16x16x32_f16(ah, bh[1], acc[ct][1], 0, 0, 0);
            acc[ct][1] = __builtin_amdgcn_mfma_f32_16x16x32_f16(ah, bl[1], acc[ct][1], 0, 0, 0);
            // pin the interleave: 1 ds_read | 1 vmem (even ct) | 4 mfma
            __builtin_amdgcn_sched_group_barrier(0x100, 1, 0);   // DS_READ
            if ((ct & 1) == 0)
                __builtin_amdgcn_sched_group_barrier(0x20, 1, 0); // VMEM_READ
            __builtin_amdgcn_sched_group_barrier(0x8, 4, 0);      // MFMA
        }
        // drain only stage(kc+1) (oldest 4 of 12); all 8 e/p stay in flight
        asm volatile("s_waitcnt vmcnt(8)" ::: "memory");
        __builtin_amdgcn_s_barrier();
        cur ^= 1;
    }

    // masked logit per token -> LDS
    #pragma unroll
    for (int st = 0; st < 2; st++) {
        float mx = acc[0][st][0];
        #pragma unroll
        for (int ct = 0; ct < CT; ct++)
            #pragma unroll
            for (int r = 0; r < 4; r++) mx = fmaxf(mx, acc[ct][st][r]);
        mx = fmaxf(mx, __shfl_xor(mx, 16));
        mx = fmaxf(mx, __shfl_xor(mx, 32));
        if (lg == 0) {
            const int si = wv * 32 + st * 16 + lr;   // token within block
            const int s  = s0 + si;
            const float mk = mask[b * Ss + s];
            l_sh[si] = mx * mk + (mk - 1.0f) * NEGV;
        }
    }
    __syncthreads();

    // block max M_b over the 128 logits
    if (t < 128) {
        float v = l_sh[t];
        #pragma unroll
        for (int o = 32; o >= 1; o >>= 1) v = fmaxf(v, __shfl_xor(v, o));
        if ((t & 63) == 0) red2[t >> 6] = v;
    }
    __syncthreads();
    const float Mb = fmaxf(red2[0], red2[1]);
    if (t < 128) w_sh[t] = expf(l_sh[t] - Mb);
    __syncthreads();
    if (t < 128) {
        float z = w_sh[t];
        #pragma unroll
        for (int o = 32; o >= 1; o >>= 1) z += __shfl_xor(z, o);
        if ((t & 63) == 0) zred[t >> 6] = z;
    }
    __syncthreads();

    // block-local ctx partial: P[d] = sum_s w_sh[s] * e[s0+s][d]  (L2-hot)
    {
        const float* eb = embeds + ((size_t)b * Ss + s0) * Dd + t * 4;
        f32x4 ca = (f32x4){0.f, 0.f, 0.f, 0.f};
        #pragma unroll 8
        for (int s = 0; s < 128; s++) {
            const float wgt = w_sh[s];
            const f32x4 ev = *(const f32x4*)(eb + (size_t)s * Dd);
            ca[0] = fmaf(wgt, ev[0], ca[0]);
            ca[1] = fmaf(wgt, ev[1], ca[1]);
            ca[2] = fmaf(wgt, ev[2], ca[2]);
            ca[3] = fmaf(wgt, ev[3], ca[3]);
        }
        *(f32x4*)(partial + ((size_t)(b * NBLK + blk)) * Dd + t * 4) = ca;
        if (t == 0) {
            mblk[b * NBLK + blk] = Mb;
            zblk[b * NBLK + blk] = zred[0] + zred[1];
        }
    }
}

// ------- Pass 2: global flash combine + tok_diag -------
__global__ __launch_bounds__(256) void k_finish(
    const float* __restrict__ mblk, const float* __restrict__ zblk,
    const float* __restrict__ partial, const float* __restrict__ tok_diag,
    float* __restrict__ out)
{
    __shared__ float cf[NBLK];
    const int b = blockIdx.x, t = threadIdx.x;

    if (t < 64) {
        const float mv = (t < NBLK) ? mblk[b * NBLK + t] : -3.4e38f;
        float M = mv;
        #pragma unroll
        for (int o = 32; o >= 1; o >>= 1) M = fmaxf(M, __shfl_xor(M, o));
        const float zv = (t < NBLK) ? zblk[b * NBLK + t] * expf(mv - M) : 0.f;
        float Z = zv;
        #pragma unroll
        for (int o = 32; o >= 1; o >>= 1) Z += __shfl_xor(Z, o);
        if (t < NBLK) cf[t] = expf(mv - M) / Z;
    }
    __syncthreads();

    const int d = t * 4;
    f32x4 a = (f32x4){0.f, 0.f, 0.f, 0.f};
    #pragma unroll
    for (int j = 0; j < NBLK; j++) {
        const float c = cf[j];
        const f32x4 p = *(const f32x4*)(partial + ((size_t)(b * NBLK + j)) * Dd + d);
        a[0] = fmaf(c, p[0], a[0]);
        a[1] = fmaf(c, p[1], a[1]);
        a[2] = fmaf(c, p[2], a[2]);
        a[3] = fmaf(c, p[3], a[3]);
    }
    const f32x4 td = *(const f32x4*)(tok_diag + d);
    f32x4 o = a * td;
    *(f32x4*)(out + (size_t)b * Dd + d) = o;
}

extern "C" void kernel_launch(void* const* d_in, const int* in_sizes, int n_in,
                              void* d_out, int out_size, void* d_ws, size_t ws_size,
                              hipStream_t stream) {
    const float* embeds    = (const float*)d_in[0];
    const float* mask      = (const float*)d_in[1];
    const float* latent    = (const float*)d_in[2];
    const float* att_diag  = (const float*)d_in[3];
    const float* tok_diag  = (const float*)d_in[4];
    const float* pos_table = (const float*)d_in[5];
    const float* tok_mult  = (const float*)d_in[6];
    const int*   rel_ids   = (const int*)d_in[7];
    float* out = (float*)d_out;

    char* ws = (char*)d_ws;
    _Float16* whi    = (_Float16*)(ws);              // 512 KB
    float*    partial= (float*)(ws + 524288);        // 2 MB
    float*    mblk   = (float*)(ws + 2621440);       // 2 KB
    float*    zblk   = (float*)(ws + 2623488);       // 2 KB

    k_prep_w<<<(Cc * Dd) / 256, 256, 0, stream>>>(latent, att_diag, whi);
    k_scores_mfma<<<Bb * NBLK, 256, 0, stream>>>(
        embeds, mask, pos_table, tok_mult, rel_ids, whi, partial, mblk, zblk);
    k_finish<<<Bb, 256, 0, stream>>>(mblk, zblk, partial, tok_diag, out);
}